// Round 9
// baseline (242.403 us; speedup 1.0000x reference)
//
#include <hip/hip_runtime.h>
#include <hip/hip_bf16.h>

// Problem constants (from reference)
#define N_PARENT 16384
#define N_CHILD (8 * N_PARENT)   // 131072
#define CC 128                   // channels
#define KK 27                    // stencil taps

// GEMM tiling: 128x128 block tile, 4 waves (2x2), 64x64 per wave, BK=32.
// A: gll16 -> triple-buffered LDS (read-ahead frags, 1 stage deep).
// B: per-lane global->VGPR frag loads (consecutive rows -> coalesced 64-B
//    sectors, L2/L1-hot weights), double-buffered regs, dist-1 prefetch.
#define BM 128
#define BN 128
#define BK 32
#define NSTAGE 108               // 27 taps x 4 c-quarters

// ws layout (bf16 element offsets)
#define XB_OFF 0
#define XB_ELEMS (N_PARENT * CC)             // 2,097,152
#define WT_OFF XB_ELEMS
#define WT_ELEMS (KK * CC * CC)              // 442,368
#define ZR_OFF (WT_OFF + WT_ELEMS)
#define ZR_ELEMS 128
#define ZR_ROW 19840                         // ZR_OFF*2/256: zero row idx (256-B rows)

typedef __attribute__((ext_vector_type(8))) __bf16 bf16x8;
typedef __attribute__((ext_vector_type(4))) float f32x4;

__device__ __forceinline__ void gll16(const void* g, void* l) {
  __builtin_amdgcn_global_load_lds(
      (const __attribute__((address_space(1))) unsigned int*)g,
      (__attribute__((address_space(3))) unsigned int*)l,
      16, 0, 0);
}

// Cast x to bf16, build w^T[k][d][c] in bf16, zero row.
__global__ void prep_kernel(const float* __restrict__ x,
                            const float* __restrict__ w,
                            __hip_bfloat16* __restrict__ ws) {
  const int stride = gridDim.x * blockDim.x;
  const int tid = blockIdx.x * blockDim.x + threadIdx.x;
  for (int i = tid; i < XB_ELEMS; i += stride)
    ws[XB_OFF + i] = __float2bfloat16(x[i]);
  for (int j = tid; j < WT_ELEMS; j += stride) {
    const int k = j / (CC * CC);
    const int rem = j - k * CC * CC;
    const int d = rem >> 7;   // output channel
    const int c = rem & 127;  // input channel
    ws[WT_OFF + j] = __float2bfloat16(w[k * CC * CC + c * CC + d]);
  }
  if (tid < ZR_ELEMS) ws[ZR_OFF + tid] = __float2bfloat16(0.0f);
}

#define WAITN(n) asm volatile("s_waitcnt vmcnt(" #n ")" ::: "memory")

// Pipeline per stage s (one barrier):
//   issue: loadB(s+1)->bF[(s+1)&1] (4 glb) ; stageA(s+2)->slot[(s+2)%3] (2 gll16)
//   WAITN(6): stage s-1's 6 vmem drained -> A(s+1) in LDS, B(s) in regs
//   barrier: all waves' A(s+1) visible
//   fragA(s+1)->aF[(s+1)&1] (4 ds_read, stay in flight under MFMAs)
//   MFMA x16 on aF[s&1], bF[s&1] (no lgkm dependency on this stage's reads)
//   lgkmcnt(0): frag reads drained (WAR-safe before slot reuse, via next barrier)
// A swizzle (BK=32, verified 0-conflict in R8): phys_chunk = chunk ^ ((row>>1)&3),
// inverse pre-applied on global source col; gll16 dest linear.
__global__ __launch_bounds__(256, 3) void upconv_kernel(
    const int* __restrict__ neigh,
    const __hip_bfloat16* __restrict__ ws,
    const float* __restrict__ bias,
    float* __restrict__ out) {
  __shared__ __align__(16) __hip_bfloat16 As[3][BM * BK];  // 24 KB
  __shared__ unsigned short ridx[BM * KK];                 // 6.75 KB

  const int tid = threadIdx.x;
  const int wv = tid >> 6;   // wave 0..3
  const int l = tid & 63;    // lane
  const int wr = wv >> 1;    // wave row (64-row strip)
  const int wc = wv & 1;     // wave col (64-col strip)
  const int row0 = blockIdx.x * BM;

  // Preload neighbor row indices (coalesced), as 256-B-row indices.
  for (int j = tid; j < BM * KK; j += 256) {
    const int nv = neigh[row0 * KK + j];
    ridx[j] = (unsigned short)((nv >= 0) ? (nv >> 3) : ZR_ROW);
  }
  __syncthreads();

  const int lr = l & 15;                                // frag row within 16
  const int coE = ((l >> 4) ^ ((lr >> 1) & 3)) * 8;     // frag chunk (elems)
  const int g16 = l >> 2;                               // staging row in group
  const int lch = ((l & 3) ^ ((l >> 3) & 3)) * 16;      // staging src col (B)

  const char* xbB = (const char*)(ws + XB_OFF);
  // B per-lane base: row d = wc*64 + n*16 + lr (stride 256 B), chunk (l>>4)*16.
  const char* wTB =
      (const char*)(ws + WT_OFF) + (wc * 64 + lr) * 256 + (l >> 4) * 16;
  const int riB0 = (wv * 32 + g16) * KK;
  const int riB1 = (wv * 32 + 16 + g16) * KK;

  f32x4 acc[4][4] = {};
  bf16x8 aF[2][4], bF[2][4];
  int r0[2], r1[2], r2[2];

  auto ridload = [&](int* r, int tap) {
    const int T = tap > 26 ? 26 : tap;
    r[0] = ((int)ridx[riB0 + T]) << 8;
    r[1] = ((int)ridx[riB1 + T]) << 8;
  };
  auto stageA = [&](int slot, int qb, const int* r) {
    gll16(xbB + r[0] + qb + lch, &As[slot][(wv * 32) * BK]);
    gll16(xbB + r[1] + qb + lch, &As[slot][(wv * 32 + 16) * BK]);
  };
  auto loadB = [&](bf16x8* b, const char* base) {
#pragma unroll
    for (int n = 0; n < 4; ++n)
      b[n] = *reinterpret_cast<const bf16x8*>(base + n * 4096);
  };
  auto fragA = [&](bf16x8* a, int slot) {
#pragma unroll
    for (int m = 0; m < 4; ++m)
      a[m] = *reinterpret_cast<const bf16x8*>(
          &As[slot][(wr * 64 + m * 16 + lr) * BK + coE]);
  };
  auto mfma16 = [&](const bf16x8* a, const bf16x8* b) {
    __builtin_amdgcn_s_setprio(1);
#pragma unroll
    for (int m = 0; m < 4; ++m)
#pragma unroll
      for (int n = 0; n < 4; ++n)
        acc[m][n] = __builtin_amdgcn_mfma_f32_16x16x32_bf16(a[m], b[n],
                                                            acc[m][n], 0, 0, 0);
    __builtin_amdgcn_s_setprio(0);
  };

  // --- prologue: B(0)->bF[0]; A(0)->slot0; A(1)->slot1; frags(0) ----------
  ridload(r2, 0);
  loadB(bF[0], wTB);       // 4 vmem (tap0, q0)
  stageA(0, 0, r2);        // 2
  stageA(1, 64, r2);       // 2
  WAITN(2);                // drain B(0)+A(0); A(1) stays in flight
  __syncthreads();
  fragA(aF[0], 0);
  asm volatile("s_waitcnt lgkmcnt(0)" ::: "memory");

  // --- main loop: 9 x 12 stages (slots %3, parity &1, quarter %4 static) --
  const char* wTt = wTB;
  for (int t = 0; t < 9; ++t) {
#pragma unroll
    for (int j = 0; j < 12; ++j) {
      const int s = 12 * t + j;
      if (s + 1 < NSTAGE)
        loadB(bF[(j + 1) & 1],
              wTt + ((j + 1) >> 2) * 32768 + ((j + 1) & 3) * 64);
      if (s + 2 < NSTAGE) {
        const int* rs = (j < 2) ? r2 : (j < 6) ? r0 : (j < 10) ? r1 : r2;
        stageA((j + 2) % 3, ((j + 2) & 3) * 64, rs);
      }
      if (s < NSTAGE - 2)       WAITN(6);
      else if (s == NSTAGE - 2) WAITN(4);
      else                      WAITN(0);
      __builtin_amdgcn_s_barrier();
      if (s + 1 < NSTAGE) fragA(aF[(j + 1) & 1], (j + 1) % 3);
      if (j == 0)      ridload(r0, 3 * t + 1);
      else if (j == 4) ridload(r1, 3 * t + 2);
      else if (j == 8) ridload(r2, 3 * t + 3);
      mfma16(aF[j & 1], bF[j & 1]);
      asm volatile("s_waitcnt lgkmcnt(0)" ::: "memory");
    }
    wTt += 98304;  // 3 taps x 32 KB
  }

  // --- epilogue: C/D layout col=lane&15, row=(lane>>4)*4+q ---------------
  float bv[4];
#pragma unroll
  for (int n = 0; n < 4; ++n) bv[n] = bias[wc * 64 + n * 16 + lr];
  const int rbase = row0 + wr * 64 + (l >> 4) * 4;
#pragma unroll
  for (int m = 0; m < 4; ++m)
#pragma unroll
    for (int n = 0; n < 4; ++n)
#pragma unroll
      for (int q = 0; q < 4; ++q)
        out[(size_t)(rbase + m * 16 + q) * CC + wc * 64 + n * 16 + lr] =
            acc[m][n][q] + bv[n];
}

extern "C" void kernel_launch(void* const* d_in, const int* in_sizes, int n_in,
                              void* d_out, int out_size, void* d_ws,
                              size_t ws_size, hipStream_t stream) {
  const float* x = (const float*)d_in[0];
  const float* w = (const float*)d_in[1];
  const float* b = (const float*)d_in[2];
  const int* neigh = (const int*)d_in[3];
  __hip_bfloat16* ws = (__hip_bfloat16*)d_ws;
  float* out = (float*)d_out;

  hipLaunchKernelGGL(prep_kernel, dim3(512), dim3(256), 0, stream, x, w, ws);
  hipLaunchKernelGGL(upconv_kernel, dim3(N_CHILD / BM), dim3(256), 0, stream,
                     neigh, ws, b, out);
}

// Round 11
// 185.182 us; speedup vs baseline: 1.3090x; 1.3090x over previous
//
#include <hip/hip_runtime.h>
#include <hip/hip_bf16.h>

// Problem constants (from reference)
#define N_PARENT 16384
#define N_CHILD (8 * N_PARENT)   // 131072
#define CC 128                   // channels
#define KK 27                    // stencil taps

#define BM 256
#define BN 128
#define BK 32

// ws layout (bf16 element offsets)
#define XB_OFF 0
#define XB_ELEMS (N_PARENT * CC)             // 2,097,152
#define WT_OFF XB_ELEMS
#define WT_ELEMS (KK * CC * CC)              // 442,368
#define ZR_OFF (WT_OFF + WT_ELEMS)           // 2,539,520
#define ZR_ELEMS 128
#define ZR_ROW 19840                         // ZR_OFF*2/256 (R8 path)
#define PZ_OFF (ZR_OFF + ZR_ELEMS)           // 2,539,648
#define PZ_ELEMS (KK * CC)                   // 3456
#define P_OFF (PZ_OFF + PZ_ELEMS)            // 2,543,104
#define P_ELEMS ((size_t)N_PARENT * KK * CC) // 56,623,104 (113.25 MB bf16)
#define NCOL (KK * CC)                       // 3456 = P row length

typedef __attribute__((ext_vector_type(8))) __bf16 bf16x8;
typedef __attribute__((ext_vector_type(4))) float f32x4;

__device__ __forceinline__ void gll16(const void* g, void* l) {
  __builtin_amdgcn_global_load_lds(
      (const __attribute__((address_space(1))) unsigned int*)g,
      (__attribute__((address_space(3))) unsigned int*)l,
      16, 0, 0);
}

// Cast x to bf16, build w^T[k][d][c] in bf16, zero rows.
__global__ void prep_kernel(const float* __restrict__ x,
                            const float* __restrict__ w,
                            __hip_bfloat16* __restrict__ ws, int zero_pz) {
  const int stride = gridDim.x * blockDim.x;
  const int tid = blockIdx.x * blockDim.x + threadIdx.x;
  for (int i = tid; i < XB_ELEMS; i += stride)
    ws[XB_OFF + i] = __float2bfloat16(x[i]);
  for (int j = tid; j < WT_ELEMS; j += stride) {
    const int k = j / (CC * CC);
    const int rem = j - k * CC * CC;
    const int d = rem >> 7;   // output channel
    const int c = rem & 127;  // input channel
    ws[WT_OFF + j] = __float2bfloat16(w[k * CC * CC + c * CC + d]);
  }
  if (tid < ZR_ELEMS) ws[ZR_OFF + tid] = __float2bfloat16(0.0f);
  if (zero_pz && tid < PZ_ELEMS) ws[PZ_OFF + tid] = __float2bfloat16(0.0f);
}

// ===========================================================================
// NEW PATH phase 1: P[p][k*128+d] = sum_c x[p,c] w[k,c,d]  (bf16 out)
// Dense GEMM M=16384, K=128, N=3456. Block tile 256x128 (bm 0..63, bn=tap
// 0..26), 4 waves (2Mx2N), wave tile 128x64, BK=32, 4 K-quarters, dbuf,
// counted vmcnt. Swizzle identical to R8 (verified 0-conflict):
// phys_chunk = chunk ^ ((row>>1)&3), inverse on global source col.
// ===========================================================================
__global__ __launch_bounds__(256, 3) void pgemm_kernel(
    const __hip_bfloat16* __restrict__ ws, __hip_bfloat16* __restrict__ Pout) {
  __shared__ __align__(16) __hip_bfloat16 As[2][BM * BK];  // 2 x 16 KB
  __shared__ __align__(16) __hip_bfloat16 Bs[2][BN * BK];  // 2 x 8 KB

  const int tid = threadIdx.x;
  const int wv = tid >> 6, l = tid & 63;
  const int wr = wv >> 1, wc = wv & 1;
  const int bm = blockIdx.x & 63;   // 64 M-blocks
  const int bn = blockIdx.x >> 6;   // 27 taps
  const int row0 = bm * BM;

  const int lr = l & 15;
  const int coE = ((l >> 4) ^ ((lr >> 1) & 3)) * 8;
  const int lch = ((l & 3) ^ ((l >> 3) & 3)) * 16;

  const char* aLane = (const char*)(ws + XB_OFF) +
                      (size_t)(row0 + wv * 64 + (l >> 2)) * 256 + lch;
  const char* wLane = (const char*)(ws + WT_OFF) + bn * 32768 +
                      (wv * 32 + (l >> 2)) * 256 + lch;

  f32x4 acc[8][4] = {};

  auto stageAB = [&](int buf, int qb) {  // 6 gll16
#pragma unroll
    for (int i = 0; i < 4; ++i)
      gll16(aLane + i * 4096 + qb, &As[buf][(wv * 64 + i * 16) * BK]);
#pragma unroll
    for (int j = 0; j < 2; ++j)
      gll16(wLane + j * 4096 + qb, &Bs[buf][(wv * 32 + j * 16) * BK]);
  };
  auto compute = [&](int buf) {
    bf16x8 a[8], b[4];
#pragma unroll
    for (int m = 0; m < 8; ++m)
      a[m] = *reinterpret_cast<const bf16x8*>(
          &As[buf][(wr * 128 + m * 16 + lr) * BK + coE]);
#pragma unroll
    for (int n = 0; n < 4; ++n)
      b[n] = *reinterpret_cast<const bf16x8*>(
          &Bs[buf][(wc * 64 + n * 16 + lr) * BK + coE]);
#pragma unroll
    for (int m = 0; m < 8; ++m)
#pragma unroll
      for (int n = 0; n < 4; ++n)
        acc[m][n] = __builtin_amdgcn_mfma_f32_16x16x32_bf16(a[m], b[n],
                                                            acc[m][n], 0, 0, 0);
  };

#define WAITN(n) asm volatile("s_waitcnt vmcnt(" #n ")" ::: "memory")
#define BAR() __builtin_amdgcn_s_barrier()

  stageAB(0, 0);  // q0
#pragma unroll
  for (int q = 0; q < 4; ++q) {
    if (q + 1 < 4) {
      stageAB((q + 1) & 1, (q + 1) * 64);  // WAR-safe: after prev BAR
      WAITN(6);
    } else {
      WAITN(0);
    }
    BAR();
    compute(q & 1);
    BAR();
  }

  // epilogue: C/D layout col=lane&15, row=(lane>>4)*4+q; P row stride 3456
  const int prow = row0 + wr * 128 + (l >> 4) * 4;
  const int pcol = bn * 128 + wc * 64;
#pragma unroll
  for (int m = 0; m < 8; ++m)
#pragma unroll
    for (int n = 0; n < 4; ++n)
#pragma unroll
      for (int q = 0; q < 4; ++q)
        Pout[(size_t)(prow + m * 16 + q) * NCOL + pcol + n * 16 + lr] =
            __float2bfloat16(acc[m][n][q]);
}

// ===========================================================================
// NEW PATH phase 2: out[n,d] = bias[d] + sum_k P[neigh[n,k]>>3][k*128+d]
// 16 lanes per child (8 channels each), 4 children/wave, 16 children/block.
// P (113 MB) is LLC-resident; gathers are 256-B contiguous segments.
// ===========================================================================
__global__ __launch_bounds__(256, 8) void gather_kernel(
    const int* __restrict__ neigh, const __hip_bfloat16* __restrict__ ws,
    const float* __restrict__ bias, float* __restrict__ out) {
  const int tid = threadIdx.x;
  const int child = blockIdx.x * 16 + (tid >> 4);
  const int ln = tid & 15;
  const int d0 = ln * 8;

  const __hip_bfloat16* P = ws + P_OFF;
  const __hip_bfloat16* PZ = ws + PZ_OFF;

  float a[8];
  {
    f32x4 b0 = *reinterpret_cast<const f32x4*>(bias + d0);
    f32x4 b1 = *reinterpret_cast<const f32x4*>(bias + d0 + 4);
#pragma unroll
    for (int j = 0; j < 4; ++j) { a[j] = b0[j]; a[4 + j] = b1[j]; }
  }

  const int* nrow = neigh + child * KK;
#pragma unroll 9
  for (int k = 0; k < KK; ++k) {
    const int nv = nrow[k];
    const __hip_bfloat16* src =
        (nv >= 0) ? (P + (size_t)(nv >> 3) * NCOL + k * 128) : (PZ + k * 128);
    bf16x8 v = *reinterpret_cast<const bf16x8*>(src + d0);
#pragma unroll
    for (int j = 0; j < 8; ++j) a[j] += (float)v[j];
  }

  float* op = out + (size_t)child * 128 + d0;
  f32x4 o0 = {a[0], a[1], a[2], a[3]};
  f32x4 o1 = {a[4], a[5], a[6], a[7]};
  *reinterpret_cast<f32x4*>(op) = o0;
  *reinterpret_cast<f32x4*>(op + 4) = o1;
}

// ===========================================================================
// FALLBACK (R8, verified 129.5 us): gather-GEMM, 256x128 tile, BK=32
// ===========================================================================
__global__ __launch_bounds__(256, 2) void upconv_kernel(
    const int* __restrict__ neigh,
    const __hip_bfloat16* __restrict__ ws,
    const float* __restrict__ bias,
    float* __restrict__ out) {
  __shared__ __align__(16) __hip_bfloat16 As[2][BM * BK];
  __shared__ __align__(16) __hip_bfloat16 Bs[2][BN * BK];
  __shared__ unsigned short ridx[BM * KK];

  const int tid = threadIdx.x;
  const int wv = tid >> 6;
  const int l = tid & 63;
  const int wr = wv >> 1;
  const int wc = wv & 1;
  const int row0 = blockIdx.x * BM;

  for (int j = tid; j < BM * KK; j += 256) {
    const int nv = neigh[row0 * KK + j];
    ridx[j] = (unsigned short)((nv >= 0) ? (nv >> 3) : ZR_ROW);
  }
  __syncthreads();

  const int lr = l & 15;
  const int coE = (((l >> 4) ^ ((lr >> 1) & 3)) * 8);
  const int lch = ((l & 3) ^ ((l >> 3) & 3)) * 16;

  const char* xbB = (const char*)(ws + XB_OFF);
  const char* wLane =
      (const char*)(ws + WT_OFF) + (wv * 32 + (l >> 2)) * 256 + lch;

  f32x4 acc[8][4] = {};

  const int riB = (wv * 64 + (l >> 2)) * KK;
  int rr[4], nr[4];
#pragma unroll
  for (int i = 0; i < 4; ++i) rr[i] = ((int)ridx[riB + i * 16 * KK]) << 8;

  auto stageA = [&](int buf, int qb, const int* r) {
#pragma unroll
    for (int i = 0; i < 4; ++i)
      gll16(xbB + r[i] + qb + lch, &As[buf][(wv * 64 + i * 16) * BK]);
  };
  auto stageB = [&](int buf, int tqb) {
#pragma unroll
    for (int j = 0; j < 2; ++j)
      gll16(wLane + tqb + j * 4096, &Bs[buf][(wv * 32 + j * 16) * BK]);
  };
  auto compute = [&](int buf) {
    bf16x8 a[8], b[4];
#pragma unroll
    for (int m = 0; m < 8; ++m)
      a[m] = *reinterpret_cast<const bf16x8*>(
          &As[buf][(wr * 128 + m * 16 + lr) * BK + coE]);
#pragma unroll
    for (int n = 0; n < 4; ++n)
      b[n] = *reinterpret_cast<const bf16x8*>(
          &Bs[buf][(wc * 64 + n * 16 + lr) * BK + coE]);
    __builtin_amdgcn_s_setprio(1);
#pragma unroll
    for (int m = 0; m < 8; ++m)
#pragma unroll
      for (int n = 0; n < 4; ++n)
        acc[m][n] = __builtin_amdgcn_mfma_f32_16x16x32_bf16(a[m], b[n],
                                                            acc[m][n], 0, 0, 0);
    __builtin_amdgcn_s_setprio(0);
  };

  stageB(0, 0);
  stageA(0, 0, rr);

  for (int k = 0; k < KK; ++k) {
    const int tb = k * 32768;

    stageB(1, tb + 64);
    stageA(1, 64, rr);
    WAITN(6); BAR();
    compute(0);
    BAR();

    stageB(0, tb + 128);
    stageA(0, 128, rr);
    WAITN(6); BAR();
    compute(1);
    BAR();

    stageB(1, tb + 192);
    stageA(1, 192, rr);
#pragma unroll
    for (int i = 0; i < 4; ++i)
      nr[i] = (k + 1 < KK) ? (((int)ridx[riB + i * 16 * KK + k + 1]) << 8)
                           : rr[i];
    WAITN(6); BAR();
    compute(0);
    BAR();

    if (k + 1 < KK) {
      stageB(0, tb + 32768);
      stageA(0, 0, nr);
      WAITN(6);
    } else {
      WAITN(0);
    }
    BAR();
    compute(1);
    BAR();

#pragma unroll
    for (int i = 0; i < 4; ++i) rr[i] = nr[i];
  }

  float bv[4];
#pragma unroll
  for (int n = 0; n < 4; ++n) bv[n] = bias[wc * 64 + n * 16 + lr];
  const int rbase = row0 + wr * 128 + (l >> 4) * 4;
#pragma unroll
  for (int m = 0; m < 8; ++m)
#pragma unroll
    for (int n = 0; n < 4; ++n)
#pragma unroll
      for (int q = 0; q < 4; ++q)
        out[(size_t)(rbase + m * 16 + q) * CC + wc * 64 + n * 16 + lr] =
            acc[m][n][q] + bv[n];
}

extern "C" void kernel_launch(void* const* d_in, const int* in_sizes, int n_in,
                              void* d_out, int out_size, void* d_ws,
                              size_t ws_size, hipStream_t stream) {
  const float* x = (const float*)d_in[0];
  const float* w = (const float*)d_in[1];
  const float* b = (const float*)d_in[2];
  const int* neigh = (const int*)d_in[3];
  __hip_bfloat16* ws = (__hip_bfloat16*)d_ws;
  float* out = (float*)d_out;

  const size_t need = ((size_t)P_OFF + P_ELEMS) * sizeof(__hip_bfloat16);
  if (ws_size >= need) {
    // Factored path: 14.5-GFLOP dense GEMM -> LLC-resident gather-sum.
    hipLaunchKernelGGL(prep_kernel, dim3(512), dim3(256), 0, stream, x, w, ws,
                       1);
    hipLaunchKernelGGL(pgemm_kernel, dim3(64 * KK), dim3(256), 0, stream, ws,
                       ws + P_OFF);
    hipLaunchKernelGGL(gather_kernel, dim3(N_CHILD / 16), dim3(256), 0, stream,
                       neigh, ws, b, out);
  } else {
    // Fallback: R8 fused gather-GEMM (129.5 us).
    hipLaunchKernelGGL(prep_kernel, dim3(512), dim3(256), 0, stream, x, w, ws,
                       0);
    hipLaunchKernelGGL(upconv_kernel, dim3(N_CHILD / BM), dim3(256), 0, stream,
                       neigh, ws, b, out);
  }
}

// Round 12
// 145.486 us; speedup vs baseline: 1.6662x; 1.2728x over previous
//
#include <hip/hip_runtime.h>
#include <hip/hip_bf16.h>

// Problem constants (from reference)
#define N_PARENT 16384
#define N_CHILD (8 * N_PARENT)   // 131072
#define CC 128                   // channels
#define KK 27                    // stencil taps

// GEMM tiling: 256x128 block tile, 4 waves (2Mx2N), wave tile 128x64, BK=32.
// R12 = R8 + FULL REGISTER READ-AHEAD: window s MFMAs run on frags read in
// window s-1 (registers only, no lgkm dependency); this window's 12 ds_reads
// (slice s+1) execute UNDER the 32-MFMA burst. LDS 61.5 KB -> 2 blocks/CU.
#define BM 256
#define BN 128
#define BK 32

// ws layout (bf16 element offsets)
#define XB_OFF 0
#define XB_ELEMS (N_PARENT * CC)             // 2,097,152
#define WT_OFF XB_ELEMS
#define WT_ELEMS (KK * CC * CC)              // 442,368
#define ZR_OFF (WT_OFF + WT_ELEMS)
#define ZR_ELEMS 128
#define ZR_ROW 19840                         // ZR_OFF*2/256: zero row idx (256-B rows)

typedef __attribute__((ext_vector_type(8))) __bf16 bf16x8;
typedef __attribute__((ext_vector_type(4))) float f32x4;

__device__ __forceinline__ void gll16(const void* g, void* l) {
  __builtin_amdgcn_global_load_lds(
      (const __attribute__((address_space(1))) unsigned int*)g,
      (__attribute__((address_space(3))) unsigned int*)l,
      16, 0, 0);
}

// Cast x to bf16, build w^T[k][d][c] in bf16, zero row.
__global__ void prep_kernel(const float* __restrict__ x,
                            const float* __restrict__ w,
                            __hip_bfloat16* __restrict__ ws) {
  const int stride = gridDim.x * blockDim.x;
  const int tid = blockIdx.x * blockDim.x + threadIdx.x;
  for (int i = tid; i < XB_ELEMS; i += stride)
    ws[XB_OFF + i] = __float2bfloat16(x[i]);
  for (int j = tid; j < WT_ELEMS; j += stride) {
    const int k = j / (CC * CC);
    const int rem = j - k * CC * CC;
    const int d = rem >> 7;   // output channel
    const int c = rem & 127;  // input channel
    ws[WT_OFF + j] = __float2bfloat16(w[k * CC * CC + c * CC + d]);
  }
  if (tid < ZR_ELEMS) ws[ZR_OFF + tid] = __float2bfloat16(0.0f);
}

// Window s (slice s = one K32 quarter; buffer parity = slice parity):
//   stage slice s+2 -> buf[s&1]   (its frag-reads drained last window)
//   vmcnt(6)                      (slice s+1 landed; s+2 stays in flight)
//   barrier
//   ds_read slice s+1 frags -> aR/bR[(s+1)&1]   (12 x ds_read_b128)
//   32 MFMA on aR/bR[s&1]         (registers only -- no lgkm wait)
//   lgkmcnt(0); barrier           (frag reads drained -> buf reuse safe)
// Swizzle (R8-verified 0-conflict): phys_chunk = chunk ^ ((row>>1)&3),
// inverse applied on global source col; gll16 dest linear.
__global__ __launch_bounds__(256, 2) void upconv_kernel(
    const int* __restrict__ neigh,
    const __hip_bfloat16* __restrict__ ws,
    const float* __restrict__ bias,
    float* __restrict__ out) {
  __shared__ __align__(16) __hip_bfloat16 As[2][BM * BK];  // 2 x 16 KB
  __shared__ __align__(16) __hip_bfloat16 Bs[2][BN * BK];  // 2 x 8 KB
  __shared__ unsigned short ridx[BM * KK];                 // 13.5 KB

  const int tid = threadIdx.x;
  const int wv = tid >> 6;   // wave 0..3
  const int l = tid & 63;    // lane
  const int wr = wv >> 1;    // wave row (128-row strip)
  const int wc = wv & 1;     // wave col (64-col strip)
  const int row0 = blockIdx.x * BM;

  // Preload neighbor row indices (coalesced), as 256-B-row indices.
  for (int j = tid; j < BM * KK; j += 256) {
    const int nv = neigh[row0 * KK + j];
    ridx[j] = (unsigned short)((nv >= 0) ? (nv >> 3) : ZR_ROW);
  }
  __syncthreads();

  const int lr = l & 15;                               // frag row within 16
  const int coE = (((l >> 4) ^ ((lr >> 1) & 3)) * 8);  // frag chunk (elems)
  const int lch = ((l & 3) ^ ((l >> 3) & 3)) * 16;     // staging src col (bytes)

  const char* xbB = (const char*)(ws + XB_OFF);
  // Per-lane B staging base: d-row = wv*32 + (l>>2), w^T row stride 256 B.
  const char* wLane =
      (const char*)(ws + WT_OFF) + (wv * 32 + (l >> 2)) * 256 + lch;

  f32x4 acc[8][4] = {};
  bf16x8 aR[2][8], bR[2][4];  // read-ahead fragment sets (ping-pong)

  // ridx indices for this lane's 4 A-staging groups (16 rows each).
  const int riB = (wv * 64 + (l >> 2)) * KK;
  int rr[4], nr[4];
#pragma unroll
  for (int i = 0; i < 4; ++i) rr[i] = ((int)ridx[riB + i * 16 * KK]) << 8;

  // --- staging: 6 gll16/wave per K32 quarter (4 A + 2 B) ------------------
  auto stageA = [&](int buf, int qb, const int* r) {
#pragma unroll
    for (int i = 0; i < 4; ++i)
      gll16(xbB + r[i] + qb + lch, &As[buf][(wv * 64 + i * 16) * BK]);
  };
  auto stageB = [&](int buf, int tqb) {  // tqb = tap*32768 + quarter byte
#pragma unroll
    for (int j = 0; j < 2; ++j)
      gll16(wLane + tqb + j * 4096, &Bs[buf][(wv * 32 + j * 16) * BK]);
  };

  // --- frag read-ahead: 12 ds_read_b128 into register set pb --------------
  auto fragRead = [&](int pb, int buf) {
#pragma unroll
    for (int m = 0; m < 8; ++m)
      aR[pb][m] = *reinterpret_cast<const bf16x8*>(
          &As[buf][(wr * 128 + m * 16 + lr) * BK + coE]);
#pragma unroll
    for (int n = 0; n < 4; ++n)
      bR[pb][n] = *reinterpret_cast<const bf16x8*>(
          &Bs[buf][(wc * 64 + n * 16 + lr) * BK + coE]);
  };

  // --- compute: 32 MFMA, register operands only ---------------------------
  auto mfma32 = [&](int pb) {
    __builtin_amdgcn_s_setprio(1);
#pragma unroll
    for (int m = 0; m < 8; ++m)
#pragma unroll
      for (int n = 0; n < 4; ++n)
        acc[m][n] = __builtin_amdgcn_mfma_f32_16x16x32_bf16(
            aR[pb][m], bR[pb][n], acc[m][n], 0, 0, 0);
    __builtin_amdgcn_s_setprio(0);
  };

#define WAITN(n) asm volatile("s_waitcnt vmcnt(" #n ")" ::: "memory")
#define LGKM0 asm volatile("s_waitcnt lgkmcnt(0)" ::: "memory")
#define BAR() __builtin_amdgcn_s_barrier()

  // --- prologue: stage slice0->buf0, slice1->buf1; frags(slice0) ----------
  stageB(0, 0);
  stageA(0, 0, rr);
  stageB(1, 64);
  stageA(1, 64, rr);
  WAITN(6);        // slice0 landed; slice1 in flight
  __syncthreads();
  fragRead(0, 0);  // slice0 -> set0
  LGKM0;
  BAR();           // all waves' reads of buf0 drained before loop stages it

  // --- main loop: 27 taps x 4 windows (slices 4k..4k+3) -------------------
  for (int k = 0; k < KK; ++k) {
    const int tb = k * 32768;  // B tap byte offset

    // window 4k: stage (k,q2)->buf0 ; read slice 4k+1 ; MFMA slice 4k
    stageB(0, tb + 128);
    stageA(0, 128, rr);
    WAITN(6); BAR();
    fragRead(1, 1);
    mfma32(0);
    LGKM0; BAR();

    // window 4k+1: stage (k,q3)->buf1 ; nr prefetch ; read 4k+2 ; MFMA 4k+1
    stageB(1, tb + 192);
    stageA(1, 192, rr);
#pragma unroll
    for (int i = 0; i < 4; ++i)
      nr[i] = (k + 1 < KK) ? (((int)ridx[riB + i * 16 * KK + k + 1]) << 8)
                           : rr[i];
    WAITN(6); BAR();
    fragRead(0, 0);
    mfma32(1);
    LGKM0; BAR();

    // window 4k+2: stage (k+1,q0)->buf0 ; read slice 4k+3 ; MFMA slice 4k+2
    if (k + 1 < KK) {
      stageB(0, tb + 32768);
      stageA(0, 0, nr);
      WAITN(6);
    } else {
      WAITN(0);  // slice 107 (last) landed
    }
    BAR();
    fragRead(1, 1);
    mfma32(0);
    LGKM0; BAR();

    // window 4k+3: stage (k+1,q1)->buf1 ; read slice 4k+4 ; MFMA slice 4k+3
    if (k + 1 < KK) {
      stageB(1, tb + 32768 + 64);
      stageA(1, 64, nr);
      WAITN(6); BAR();
      fragRead(0, 0);
      mfma32(1);
      LGKM0; BAR();
    } else {
      mfma32(1);  // final window: registers only
    }

#pragma unroll
    for (int i = 0; i < 4; ++i) rr[i] = nr[i];
  }

  // --- epilogue: C/D layout col=lane&15, row=(lane>>4)*4+q ---------------
  float bv[4];
#pragma unroll
  for (int n = 0; n < 4; ++n) bv[n] = bias[wc * 64 + n * 16 + lr];
  const int rbase = row0 + wr * 128 + (l >> 4) * 4;
#pragma unroll
  for (int m = 0; m < 8; ++m)
#pragma unroll
    for (int n = 0; n < 4; ++n)
#pragma unroll
      for (int q = 0; q < 4; ++q)
        out[(size_t)(rbase + m * 16 + q) * CC + wc * 64 + n * 16 + lr] =
            acc[m][n][q] + bv[n];
}

extern "C" void kernel_launch(void* const* d_in, const int* in_sizes, int n_in,
                              void* d_out, int out_size, void* d_ws,
                              size_t ws_size, hipStream_t stream) {
  const float* x = (const float*)d_in[0];
  const float* w = (const float*)d_in[1];
  const float* b = (const float*)d_in[2];
  const int* neigh = (const int*)d_in[3];
  __hip_bfloat16* ws = (__hip_bfloat16*)d_ws;
  float* out = (float*)d_out;

  hipLaunchKernelGGL(prep_kernel, dim3(512), dim3(256), 0, stream, x, w, ws);
  hipLaunchKernelGGL(upconv_kernel, dim3(N_CHILD / BM), dim3(256), 0, stream,
                     neigh, ws, b, out);
}

// Round 13
// 144.863 us; speedup vs baseline: 1.6733x; 1.0043x over previous
//
#include <hip/hip_runtime.h>
#include <hip/hip_bf16.h>

// Problem constants (from reference)
#define N_PARENT 16384
#define N_CHILD (8 * N_PARENT)   // 131072
#define CC 128                   // channels
#define KK 27                    // stencil taps

// GEMM tiling: 256x128 block tile, 4 waves (2Mx2N), wave tile 128x64, BK=32.
// R13 = R8 with v_mfma_f32_32x32x16_bf16 (15% fewer matrix-pipe cycles,
// half the MFMA instructions; identical LDS traffic). Staging/sync/swizzle
// byte-identical to R8 (129.5 us, 0 bank conflicts, FETCH 39 MB).
#define BM 256
#define BN 128
#define BK 32

// ws layout (bf16 element offsets)
#define XB_OFF 0
#define XB_ELEMS (N_PARENT * CC)             // 2,097,152
#define WT_OFF XB_ELEMS
#define WT_ELEMS (KK * CC * CC)              // 442,368
#define ZR_OFF (WT_OFF + WT_ELEMS)
#define ZR_ELEMS 128
#define ZR_ROW 19840                         // ZR_OFF*2/256: zero row idx (256-B rows)

typedef __attribute__((ext_vector_type(8))) __bf16 bf16x8;
typedef __attribute__((ext_vector_type(4))) float f32x4;
typedef __attribute__((ext_vector_type(16))) float f32x16;

__device__ __forceinline__ void gll16(const void* g, void* l) {
  __builtin_amdgcn_global_load_lds(
      (const __attribute__((address_space(1))) unsigned int*)g,
      (__attribute__((address_space(3))) unsigned int*)l,
      16, 0, 0);
}

// Cast x to bf16, build w^T[k][d][c] in bf16, zero row.
__global__ void prep_kernel(const float* __restrict__ x,
                            const float* __restrict__ w,
                            __hip_bfloat16* __restrict__ ws) {
  const int stride = gridDim.x * blockDim.x;
  const int tid = blockIdx.x * blockDim.x + threadIdx.x;
  for (int i = tid; i < XB_ELEMS; i += stride)
    ws[XB_OFF + i] = __float2bfloat16(x[i]);
  for (int j = tid; j < WT_ELEMS; j += stride) {
    const int k = j / (CC * CC);
    const int rem = j - k * CC * CC;
    const int d = rem >> 7;   // output channel
    const int c = rem & 127;  // input channel
    ws[WT_OFF + j] = __float2bfloat16(w[k * CC * CC + c * CC + d]);
  }
  if (tid < ZR_ELEMS) ws[ZR_OFF + tid] = __float2bfloat16(0.0f);
}

// Swizzle (R8-verified): LDS phys_chunk = log_chunk ^ ((row>>1)&3), inverse
// pre-applied on the global source column (gll16 dest linear).
// 32x32 frag reads: lane reads row (l&31), logical chunk kh*2+(l>>5);
// 8-lane batches cover all 32 banks exactly once -> conflict-free.
// Sync: R8's counted-vmcnt dbuf (6 vmem/slice, WAITN(6), 2 barriers/slice).
__global__ __launch_bounds__(256, 2) void upconv_kernel(
    const int* __restrict__ neigh,
    const __hip_bfloat16* __restrict__ ws,
    const float* __restrict__ bias,
    float* __restrict__ out) {
  __shared__ __align__(16) __hip_bfloat16 As[2][BM * BK];  // 2 x 16 KB
  __shared__ __align__(16) __hip_bfloat16 Bs[2][BN * BK];  // 2 x 8 KB
  __shared__ unsigned short ridx[BM * KK];                 // 13.5 KB

  const int tid = threadIdx.x;
  const int wv = tid >> 6;   // wave 0..3
  const int l = tid & 63;    // lane
  const int wr = wv >> 1;    // wave row (128-row strip)
  const int wc = wv & 1;     // wave col (64-col strip)
  const int row0 = blockIdx.x * BM;

  // Preload neighbor row indices (coalesced), as 256-B-row indices.
  for (int j = tid; j < BM * KK; j += 256) {
    const int nv = neigh[row0 * KK + j];
    ridx[j] = (unsigned short)((nv >= 0) ? (nv >> 3) : ZR_ROW);
  }
  __syncthreads();

  const int l31 = l & 31;                              // frag row within 32
  const int sw32 = (l >> 1) & 3;                       // ((row)>>1)&3 term
  // logical chunk for k-half kh: kh*2 + (l>>5); element offsets:
  const int ce0 = (((l >> 5) ^ sw32)) * 8;             // kh=0
  const int ce1 = ((2 + (l >> 5)) ^ sw32) * 8;         // kh=1
  const int lch = ((l & 3) ^ ((l >> 3) & 3)) * 16;     // staging src col (bytes)

  const char* xbB = (const char*)(ws + XB_OFF);
  // Per-lane B staging base: d-row = wv*32 + (l>>2), w^T row stride 256 B.
  const char* wLane =
      (const char*)(ws + WT_OFF) + (wv * 32 + (l >> 2)) * 256 + lch;

  f32x16 acc[4][2] = {};

  // ridx indices for this lane's 4 A-staging groups (16 rows each).
  const int riB = (wv * 64 + (l >> 2)) * KK;
  int rr[4], nr[4];
#pragma unroll
  for (int i = 0; i < 4; ++i) rr[i] = ((int)ridx[riB + i * 16 * KK]) << 8;

  // --- staging: 6 gll16/wave per K32 slice (4 A + 2 B) --------------------
  auto stageA = [&](int buf, int qb, const int* r) {
#pragma unroll
    for (int i = 0; i < 4; ++i)
      gll16(xbB + r[i] + qb + lch, &As[buf][(wv * 64 + i * 16) * BK]);
  };
  auto stageB = [&](int buf, int tqb) {  // tqb = tap*32768 + quarter byte
#pragma unroll
    for (int j = 0; j < 2; ++j)
      gll16(wLane + tqb + j * 4096, &Bs[buf][(wv * 32 + j * 16) * BK]);
  };

  // --- compute: 12 ds_read_b128 + 8 MFMA(32x32x16) per K32 slice ----------
  auto compute = [&](int buf) {
    bf16x8 a[4][2], b[2][2];
#pragma unroll
    for (int mt = 0; mt < 4; ++mt) {
      const int rb = (wr * 128 + mt * 32 + l31) * BK;
      a[mt][0] = *reinterpret_cast<const bf16x8*>(&As[buf][rb + ce0]);
      a[mt][1] = *reinterpret_cast<const bf16x8*>(&As[buf][rb + ce1]);
    }
#pragma unroll
    for (int nt = 0; nt < 2; ++nt) {
      const int rb = (wc * 64 + nt * 32 + l31) * BK;
      b[nt][0] = *reinterpret_cast<const bf16x8*>(&Bs[buf][rb + ce0]);
      b[nt][1] = *reinterpret_cast<const bf16x8*>(&Bs[buf][rb + ce1]);
    }
    __builtin_amdgcn_s_setprio(1);
#pragma unroll
    for (int kh = 0; kh < 2; ++kh)
#pragma unroll
      for (int mt = 0; mt < 4; ++mt)
#pragma unroll
        for (int nt = 0; nt < 2; ++nt)
          acc[mt][nt] = __builtin_amdgcn_mfma_f32_32x32x16_bf16(
              a[mt][kh], b[nt][kh], acc[mt][nt], 0, 0, 0);
    __builtin_amdgcn_s_setprio(0);
  };

#define WAITN(n) asm volatile("s_waitcnt vmcnt(" #n ")" ::: "memory")
#define BAR() __builtin_amdgcn_s_barrier()

  // --- prologue: stage (tap0, q0) -> buf0 ---------------------------------
  stageB(0, 0);
  stageA(0, 0, rr);

  // --- main loop: 27 taps x 4 c-quarters (identical to R8) ----------------
  for (int k = 0; k < KK; ++k) {
    const int tb = k * 32768;  // B tap byte offset (2*CC*CC bytes)

    stageB(1, tb + 64);
    stageA(1, 64, rr);
    WAITN(6); BAR();
    compute(0);
    BAR();

    stageB(0, tb + 128);
    stageA(0, 128, rr);
    WAITN(6); BAR();
    compute(1);
    BAR();

    stageB(1, tb + 192);
    stageA(1, 192, rr);
#pragma unroll
    for (int i = 0; i < 4; ++i)
      nr[i] = (k + 1 < KK) ? (((int)ridx[riB + i * 16 * KK + k + 1]) << 8)
                           : rr[i];
    WAITN(6); BAR();
    compute(0);
    BAR();

    if (k + 1 < KK) {
      stageB(0, tb + 32768);
      stageA(0, 0, nr);
      WAITN(6);
    } else {
      WAITN(0);
    }
    BAR();
    compute(1);
    BAR();

#pragma unroll
    for (int i = 0; i < 4; ++i) rr[i] = nr[i];
  }

  // --- epilogue: 32x32 C/D layout col=lane&31, row=(q&3)+8*(q>>2)+4*(l>>5)
  float bv[2];
#pragma unroll
  for (int nt = 0; nt < 2; ++nt) bv[nt] = bias[wc * 64 + nt * 32 + l31];
  const int rbase = row0 + wr * 128 + 4 * (l >> 5);
#pragma unroll
  for (int mt = 0; mt < 4; ++mt)
#pragma unroll
    for (int nt = 0; nt < 2; ++nt)
#pragma unroll
      for (int q = 0; q < 16; ++q) {
        const int row = rbase + mt * 32 + (q & 3) + 8 * (q >> 2);
        out[(size_t)row * CC + wc * 64 + nt * 32 + l31] =
            acc[mt][nt][q] + bv[nt];
      }
}

extern "C" void kernel_launch(void* const* d_in, const int* in_sizes, int n_in,
                              void* d_out, int out_size, void* d_ws,
                              size_t ws_size, hipStream_t stream) {
  const float* x = (const float*)d_in[0];
  const float* w = (const float*)d_in[1];
  const float* b = (const float*)d_in[2];
  const int* neigh = (const int*)d_in[3];
  __hip_bfloat16* ws = (__hip_bfloat16*)d_ws;
  float* out = (float*)d_out;

  hipLaunchKernelGGL(prep_kernel, dim3(512), dim3(256), 0, stream, x, w, ws);
  hipLaunchKernelGGL(upconv_kernel, dim3(N_CHILD / BM), dim3(256), 0, stream,
                     neigh, ws, b, out);
}

// Round 14
// 129.713 us; speedup vs baseline: 1.8688x; 1.1168x over previous
//
#include <hip/hip_runtime.h>
#include <hip/hip_bf16.h>

// Problem constants (from reference)
#define N_PARENT 16384
#define N_CHILD (8 * N_PARENT)   // 131072
#define CC 128                   // channels
#define KK 27                    // stencil taps

// GEMM tiling: 256x128 block tile, 4 waves (2Mx2N), wave tile 128x64, BK=32.
// BEST CONFIG (R8, 129.5 us): 16x16x32 MFMA, swizzle chunk^((row>>1)&3)
// (0 bank conflicts), counted-vmcnt dbuf, 2 blocks/CU.
// Session findings: serial-pipe sum MFMA(56us)+LDS(59us)+VALU(20us) ~= wall;
// intra-block overlap unreachable at this geometry (N=128 blocks the 256^2
// 8-phase structure); 32x32 MFMA conflicts (R13); factorization loses to
// HBM gather (R11); A-or-B-in-registers loses to coalescing (R5/R9/R12).
#define BM 256
#define BN 128
#define BK 32

// ws layout (bf16 element offsets)
#define XB_OFF 0
#define XB_ELEMS (N_PARENT * CC)             // 2,097,152
#define WT_OFF XB_ELEMS
#define WT_ELEMS (KK * CC * CC)              // 442,368
#define ZR_OFF (WT_OFF + WT_ELEMS)
#define ZR_ELEMS 128
#define ZR_ROW 19840                         // ZR_OFF*2/256: zero row idx (256-B rows)

typedef __attribute__((ext_vector_type(8))) __bf16 bf16x8;
typedef __attribute__((ext_vector_type(4))) float f32x4;

__device__ __forceinline__ void gll16(const void* g, void* l) {
  __builtin_amdgcn_global_load_lds(
      (const __attribute__((address_space(1))) unsigned int*)g,
      (__attribute__((address_space(3))) unsigned int*)l,
      16, 0, 0);
}

// Cast x to bf16, build w^T[k][d][c] in bf16, zero row.
__global__ void prep_kernel(const float* __restrict__ x,
                            const float* __restrict__ w,
                            __hip_bfloat16* __restrict__ ws) {
  const int stride = gridDim.x * blockDim.x;
  const int tid = blockIdx.x * blockDim.x + threadIdx.x;
  for (int i = tid; i < XB_ELEMS; i += stride)
    ws[XB_OFF + i] = __float2bfloat16(x[i]);
  for (int j = tid; j < WT_ELEMS; j += stride) {
    const int k = j / (CC * CC);
    const int rem = j - k * CC * CC;
    const int d = rem >> 7;   // output channel
    const int c = rem & 127;  // input channel
    ws[WT_OFF + j] = __float2bfloat16(w[k * CC * CC + c * CC + d]);
  }
  if (tid < ZR_ELEMS) ws[ZR_OFF + tid] = __float2bfloat16(0.0f);
}

// BK=32 swizzle (verified 0 conflicts): phys_chunk = chunk ^ ((row>>1)&3),
// inverse applied on the global source column (gll16 dest linear).
// Sync per K32 slice: issue next slice's 6 gll16 -> vmcnt(6) (this slice
// landed, next in flight) -> barrier -> 12 ds_read_b128 + 32 MFMA -> barrier.
__global__ __launch_bounds__(256, 2) void upconv_kernel(
    const int* __restrict__ neigh,
    const __hip_bfloat16* __restrict__ ws,
    const float* __restrict__ bias,
    float* __restrict__ out) {
  __shared__ __align__(16) __hip_bfloat16 As[2][BM * BK];  // 2 x 16 KB
  __shared__ __align__(16) __hip_bfloat16 Bs[2][BN * BK];  // 2 x 8 KB
  __shared__ unsigned short ridx[BM * KK];                 // 13.5 KB

  const int tid = threadIdx.x;
  const int wv = tid >> 6;   // wave 0..3
  const int l = tid & 63;    // lane
  const int wr = wv >> 1;    // wave row (128-row strip)
  const int wc = wv & 1;     // wave col (64-col strip)
  const int row0 = blockIdx.x * BM;

  // Preload neighbor row indices (coalesced), as 256-B-row indices.
  for (int j = tid; j < BM * KK; j += 256) {
    const int nv = neigh[row0 * KK + j];
    ridx[j] = (unsigned short)((nv >= 0) ? (nv >> 3) : ZR_ROW);
  }
  __syncthreads();

  const int lr = l & 15;                               // frag row within 16
  const int coE = (((l >> 4) ^ ((lr >> 1) & 3)) * 8);  // frag chunk (elems)
  const int lch = ((l & 3) ^ ((l >> 3) & 3)) * 16;     // staging src col (bytes)

  const char* xbB = (const char*)(ws + XB_OFF);
  // Per-lane B staging base: d-row = wv*32 + (l>>2), w^T row stride 256 B.
  const char* wLane =
      (const char*)(ws + WT_OFF) + (wv * 32 + (l >> 2)) * 256 + lch;

  f32x4 acc[8][4] = {};

  // ridx indices for this lane's 4 A-staging groups (16 rows each).
  const int riB = (wv * 64 + (l >> 2)) * KK;
  int rr[4], nr[4];
#pragma unroll
  for (int i = 0; i < 4; ++i) rr[i] = ((int)ridx[riB + i * 16 * KK]) << 8;

  // --- staging: 6 gll16/wave per K32 slice (4 A + 2 B) --------------------
  auto stageA = [&](int buf, int qb, const int* r) {
#pragma unroll
    for (int i = 0; i < 4; ++i)
      gll16(xbB + r[i] + qb + lch, &As[buf][(wv * 64 + i * 16) * BK]);
  };
  auto stageB = [&](int buf, int tqb) {  // tqb = tap*32768 + quarter byte
#pragma unroll
    for (int j = 0; j < 2; ++j)
      gll16(wLane + tqb + j * 4096, &Bs[buf][(wv * 32 + j * 16) * BK]);
  };

  // --- compute: 12 ds_read_b128 + 32 MFMA per K32 slice -------------------
  auto compute = [&](int buf) {
    bf16x8 a[8], b[4];
#pragma unroll
    for (int m = 0; m < 8; ++m)
      a[m] = *reinterpret_cast<const bf16x8*>(
          &As[buf][(wr * 128 + m * 16 + lr) * BK + coE]);
#pragma unroll
    for (int n = 0; n < 4; ++n)
      b[n] = *reinterpret_cast<const bf16x8*>(
          &Bs[buf][(wc * 64 + n * 16 + lr) * BK + coE]);
    __builtin_amdgcn_s_setprio(1);
#pragma unroll
    for (int m = 0; m < 8; ++m)
#pragma unroll
      for (int n = 0; n < 4; ++n)
        acc[m][n] = __builtin_amdgcn_mfma_f32_16x16x32_bf16(a[m], b[n],
                                                            acc[m][n], 0, 0, 0);
    __builtin_amdgcn_s_setprio(0);
  };

#define WAITN(n) asm volatile("s_waitcnt vmcnt(" #n ")" ::: "memory")
#define BAR() __builtin_amdgcn_s_barrier()

  // --- prologue: stage (tap0, q0) -> buf0 ---------------------------------
  stageB(0, 0);
  stageA(0, 0, rr);

  // --- main loop: 27 taps x 4 c-quarters ----------------------------------
  for (int k = 0; k < KK; ++k) {
    const int tb = k * 32768;  // B tap byte offset (2*CC*CC bytes)

    stageB(1, tb + 64);
    stageA(1, 64, rr);
    WAITN(6); BAR();
    compute(0);
    BAR();

    stageB(0, tb + 128);
    stageA(0, 128, rr);
    WAITN(6); BAR();
    compute(1);
    BAR();

    stageB(1, tb + 192);
    stageA(1, 192, rr);
#pragma unroll
    for (int i = 0; i < 4; ++i)
      nr[i] = (k + 1 < KK) ? (((int)ridx[riB + i * 16 * KK + k + 1]) << 8)
                           : rr[i];
    WAITN(6); BAR();
    compute(0);
    BAR();

    if (k + 1 < KK) {
      stageB(0, tb + 32768);
      stageA(0, 0, nr);
      WAITN(6);
    } else {
      WAITN(0);
    }
    BAR();
    compute(1);
    BAR();

#pragma unroll
    for (int i = 0; i < 4; ++i) rr[i] = nr[i];
  }

  // --- epilogue: C/D layout col=lane&15, row=(lane>>4)*4+q ---------------
  float bv[4];
#pragma unroll
  for (int n = 0; n < 4; ++n) bv[n] = bias[wc * 64 + n * 16 + lr];
  const int rbase = row0 + wr * 128 + (l >> 4) * 4;
#pragma unroll
  for (int m = 0; m < 8; ++m)
#pragma unroll
    for (int n = 0; n < 4; ++n)
#pragma unroll
      for (int q = 0; q < 4; ++q)
        out[(size_t)(rbase + m * 16 + q) * CC + wc * 64 + n * 16 + lr] =
            acc[m][n][q] + bv[n];
}

extern "C" void kernel_launch(void* const* d_in, const int* in_sizes, int n_in,
                              void* d_out, int out_size, void* d_ws,
                              size_t ws_size, hipStream_t stream) {
  const float* x = (const float*)d_in[0];
  const float* w = (const float*)d_in[1];
  const float* b = (const float*)d_in[2];
  const int* neigh = (const int*)d_in[3];
  __hip_bfloat16* ws = (__hip_bfloat16*)d_ws;
  float* out = (float*)d_out;

  hipLaunchKernelGGL(prep_kernel, dim3(512), dim3(256), 0, stream, x, w, ws);
  hipLaunchKernelGGL(upconv_kernel, dim3(N_CHILD / BM), dim3(256), 0, stream,
                     neigh, ws, b, out);
}